// Round 3
// baseline (100.831 us; speedup 1.0000x reference)
//
#include <hip/hip_runtime.h>

#define NB 65536
#define NJ 32
#define BLK 128   // threads per block (rows per block)

struct V3 { float x, y, z; };
struct Q4 { float x, y, z, w; };

__device__ __forceinline__ V3 v3cross(V3 a, V3 b) {
    V3 r;
    r.x = a.y * b.z - a.z * b.y;
    r.y = a.z * b.x - a.x * b.z;
    r.z = a.x * b.y - a.y * b.x;
    return r;
}

// reference: w = w1*w2 - v1.v2 ; v = w1*v2 + w2*v1 + v1 x v2
__device__ __forceinline__ Q4 qmul(Q4 a, Q4 b) {
    Q4 r;
    r.x = a.w * b.x + b.w * a.x + (a.y * b.z - a.z * b.y);
    r.y = a.w * b.y + b.w * a.y + (a.z * b.x - a.x * b.z);
    r.z = a.w * b.z + b.w * a.z + (a.x * b.y - a.y * b.x);
    r.w = a.w * b.w - (a.x * b.x + a.y * b.y + a.z * b.z);
    return r;
}

// reference: t + 2*cross(v, cross(v,t) + w*t)
__device__ __forceinline__ V3 qrot(Q4 q, V3 t) {
    V3 v = {q.x, q.y, q.z};
    V3 u = v3cross(v, t);
    u.x += q.w * t.x; u.y += q.w * t.y; u.z += q.w * t.z;
    V3 c = v3cross(v, u);
    V3 r = {t.x + 2.f * c.x, t.y + 2.f * c.y, t.z + 2.f * c.z};
    return r;
}

__device__ __forceinline__ V3 quat_log(Q4 q) {
    float s = (q.w < 0.f) ? -1.f : 1.f;
    float x = q.x * s, y = q.y * s, z = q.z * s, w = q.w * s;
    float nv2 = x * x + y * y + z * z;
    float nv = sqrtf(fmaxf(nv2, 1e-14f));
    float angle = 2.f * atan2f(nv, w);
    float w_safe = (fabsf(w) > 1e-8f) ? w : 1.f;
    float scale = (nv < 1e-6f) ? (2.f / w_safe) : (angle / nv);
    V3 r = {x * scale, y * scale, z * scale};
    return r;
}

__device__ __forceinline__ void se3_log(V3 t, Q4 q, float* o6) {
    V3 phi = quat_log(q);
    float th2 = phi.x * phi.x + phi.y * phi.y + phi.z * phi.z;
    float th = sqrtf(fmaxf(th2, 1e-14f));
    bool small = th < 1e-4f;
    float ths = small ? 1.f : th;
    float sn = sinf(ths), cs = cosf(ths);
    float a_big = (1.f - ths * sn / (2.f * (1.f - cs))) / (ths * ths);
    float a = small ? (1.f / 12.f + th2 / 720.f) : a_big;
    V3 pt = v3cross(phi, t);
    V3 ppt = v3cross(phi, pt);
    o6[0] = t.x - 0.5f * pt.x + a * ppt.x;
    o6[1] = t.y - 0.5f * pt.y + a * ppt.y;
    o6[2] = t.z - 0.5f * pt.z + a * ppt.z;
    o6[3] = phi.x;
    o6[4] = phi.y;
    o6[5] = phi.z;
}

__global__ __launch_bounds__(BLK) void ik_kernel(
    const float* __restrict__ cfg,    // (B,32) f32
    const float* __restrict__ base,   // (B,7)  f32
    const float* __restrict__ tposes, // (4,7)
    const float* __restrict__ dbase,  // (7,)
    const float* __restrict__ restc,  // (32,)
    const float* __restrict__ joff,   // (32,7)
    const float* __restrict__ jaxes,  // (32,3)
    const float* __restrict__ jlo,    // (32,)
    const float* __restrict__ jup,    // (32,)
    float* __restrict__ out)          // (B,94) f32
{
    __shared__ float s_offt[NJ][3];
    __shared__ float s_offq[NJ][4];
    __shared__ float s_ax[NJ][3];
    __shared__ float s_lo[NJ];
    __shared__ float s_up[NJ];
    __shared__ float s_rest[NJ];
    __shared__ float s_ti[4][7];   // inverse target poses
    __shared__ float s_dbi[7];     // inverse default base
    __shared__ __align__(16) float s_out[BLK * 94];  // 48128 B staging

    const int tid = threadIdx.x;

    if (tid < NJ) {
        const int j = tid;
        s_offt[j][0] = joff[j * 7 + 0];
        s_offt[j][1] = joff[j * 7 + 1];
        s_offt[j][2] = joff[j * 7 + 2];
        s_offq[j][0] = joff[j * 7 + 3];
        s_offq[j][1] = joff[j * 7 + 4];
        s_offq[j][2] = joff[j * 7 + 5];
        s_offq[j][3] = joff[j * 7 + 6];
        s_ax[j][0] = jaxes[j * 3 + 0];
        s_ax[j][1] = jaxes[j * 3 + 1];
        s_ax[j][2] = jaxes[j * 3 + 2];
        s_lo[j] = jlo[j];
        s_up[j] = jup[j];
        s_rest[j] = restc[j];
    } else if (tid < 36) {
        const int i = tid - 32;
        V3 t = {tposes[i * 7 + 0], tposes[i * 7 + 1], tposes[i * 7 + 2]};
        Q4 q = {tposes[i * 7 + 3], tposes[i * 7 + 4], tposes[i * 7 + 5], tposes[i * 7 + 6]};
        Q4 qi = {-q.x, -q.y, -q.z, q.w};
        V3 rt = qrot(qi, t);
        s_ti[i][0] = -rt.x; s_ti[i][1] = -rt.y; s_ti[i][2] = -rt.z;
        s_ti[i][3] = qi.x;  s_ti[i][4] = qi.y;  s_ti[i][5] = qi.z;  s_ti[i][6] = qi.w;
    } else if (tid == 36) {
        V3 t = {dbase[0], dbase[1], dbase[2]};
        Q4 q = {dbase[3], dbase[4], dbase[5], dbase[6]};
        Q4 qi = {-q.x, -q.y, -q.z, q.w};
        V3 rt = qrot(qi, t);
        s_dbi[0] = -rt.x; s_dbi[1] = -rt.y; s_dbi[2] = -rt.z;
        s_dbi[3] = qi.x;  s_dbi[4] = qi.y;  s_dbi[5] = qi.z;  s_dbi[6] = qi.w;
    }
    __syncthreads();

    const int b = blockIdx.x * BLK + tid;

    // ---- load cfg row (32 f32 = 128 B) with 8x 16B vector loads ----
    float cf[NJ];
    {
        const float4* cp = reinterpret_cast<const float4*>(cfg + (size_t)b * NJ);
        #pragma unroll
        for (int v = 0; v < 8; ++v) {
            float4 d = cp[v];
            cf[v * 4 + 0] = d.x;
            cf[v * 4 + 1] = d.y;
            cf[v * 4 + 2] = d.z;
            cf[v * 4 + 3] = d.w;
        }
    }

    // ---- load base pose ----
    const float* bp = base + (size_t)b * 7;
    V3 b_t = {bp[0], bp[1], bp[2]};
    Q4 b_q = {bp[3], bp[4], bp[5], bp[6]};

    float* o = s_out + tid * 94;

    // ---- forward kinematics scan ----
    V3 Tt = b_t;
    Q4 Tq = b_q;
    #pragma unroll
    for (int j = 0; j < NJ; ++j) {
        V3 ot = {s_offt[j][0], s_offt[j][1], s_offt[j][2]};
        Q4 oq = {s_offq[j][0], s_offq[j][1], s_offq[j][2], s_offq[j][3]};
        V3 rt = qrot(Tq, ot);
        Tt.x += rt.x; Tt.y += rt.y; Tt.z += rt.z;
        Tq = qmul(Tq, oq);
        float half = 0.5f * cf[j];
        float sh, ch;
        sincosf(half, &sh, &ch);
        Q4 jq = {s_ax[j][0] * sh, s_ax[j][1] * sh, s_ax[j][2] * sh, ch};
        Tq = qmul(Tq, jq);

        if ((j & 7) == 7) {
            const int i = j >> 3;  // target index 0..3
            V3 it = {s_ti[i][0], s_ti[i][1], s_ti[i][2]};
            Q4 iq = {s_ti[i][3], s_ti[i][4], s_ti[i][5], s_ti[i][6]};
            // T_err = compose(inv(target), actual)
            V3 et = qrot(iq, Tt);
            et.x += it.x; et.y += it.y; et.z += it.z;
            Q4 eq = qmul(iq, Tq);
            float l6[6];
            se3_log(et, eq, l6);
            o[i * 6 + 0] = l6[0];          // POS_W * POSE_W = 1.0
            o[i * 6 + 1] = l6[1];
            o[i * 6 + 2] = l6[2];
            o[i * 6 + 3] = l6[3] * 0.5f;   // ORI_W * POSE_W = 0.5
            o[i * 6 + 4] = l6[4] * 0.5f;
            o[i * 6 + 5] = l6[5] * 0.5f;
        }
    }

    // ---- limit + rest residuals ----
    #pragma unroll
    for (int j = 0; j < NJ; ++j) {
        float c = cf[j];
        float lim = (fmaxf(c - s_up[j], 0.f) + fminf(c - s_lo[j], 0.f)) * 10.f;
        o[24 + j] = lim;
        o[56 + j] = (c - s_rest[j]) * 0.1f;
    }

    // ---- base residual ----
    {
        V3 it = {s_dbi[0], s_dbi[1], s_dbi[2]};
        Q4 iq = {s_dbi[3], s_dbi[4], s_dbi[5], s_dbi[6]};
        V3 et = qrot(iq, b_t);
        et.x += it.x; et.y += it.y; et.z += it.z;
        Q4 eq = qmul(iq, b_q);
        float l6[6];
        se3_log(et, eq, l6);
        o[88] = l6[0] * 5.f;
        o[89] = l6[1] * 5.f;
        o[90] = l6[2] * 5.f;
        o[91] = l6[3] * 5.f;
        o[92] = l6[4] * 5.f;
        o[93] = l6[5] * 5.f;
    }

    __syncthreads();

    // ---- coalesced flush: BLK rows * 94 f32 = 48128 B contiguous ----
    {
        const uint4* src = reinterpret_cast<const uint4*>(s_out);       // 3008 uint4
        uint4* dst = reinterpret_cast<uint4*>(out + (size_t)blockIdx.x * BLK * 94);
        #pragma unroll
        for (int i = 0; i < 24; ++i) {
            int idx = i * BLK + tid;
            if (idx < 3008) dst[idx] = src[idx];
        }
    }
}

extern "C" void kernel_launch(void* const* d_in, const int* in_sizes, int n_in,
                              void* d_out, int out_size, void* d_ws, size_t ws_size,
                              hipStream_t stream) {
    const float* cfg   = (const float*)d_in[0];
    const float* base  = (const float*)d_in[1];
    const float* tp    = (const float*)d_in[2];
    const float* db    = (const float*)d_in[3];
    const float* rest  = (const float*)d_in[4];
    const float* joff  = (const float*)d_in[5];
    const float* jax   = (const float*)d_in[6];
    const float* jlo   = (const float*)d_in[7];
    const float* jup   = (const float*)d_in[8];
    float* out = (float*)d_out;

    ik_kernel<<<NB / BLK, BLK, 0, stream>>>(cfg, base, tp, db, rest, joff, jax, jlo, jup, out);
}

// Round 4
// 91.598 us; speedup vs baseline: 1.1008x; 1.1008x over previous
//
#include <hip/hip_runtime.h>

#define NJ 32
#define ROWS_PER_BLK 64
#define BLK 256                      // 4 lanes per row * 64 rows
#define NB 65536

struct V3 { float x, y, z; };
struct Q4 { float x, y, z, w; };

__device__ __forceinline__ V3 v3cross(V3 a, V3 b) {
    V3 r;
    r.x = a.y * b.z - a.z * b.y;
    r.y = a.z * b.x - a.x * b.z;
    r.z = a.x * b.y - a.y * b.x;
    return r;
}

// reference: w = w1*w2 - v1.v2 ; v = w1*v2 + w2*v1 + v1 x v2
__device__ __forceinline__ Q4 qmul(Q4 a, Q4 b) {
    Q4 r;
    r.x = a.w * b.x + b.w * a.x + (a.y * b.z - a.z * b.y);
    r.y = a.w * b.y + b.w * a.y + (a.z * b.x - a.x * b.z);
    r.z = a.w * b.z + b.w * a.z + (a.x * b.y - a.y * b.x);
    r.w = a.w * b.w - (a.x * b.x + a.y * b.y + a.z * b.z);
    return r;
}

// reference: t + 2*cross(v, cross(v,t) + w*t)
__device__ __forceinline__ V3 qrot(Q4 q, V3 t) {
    V3 v = {q.x, q.y, q.z};
    V3 u = v3cross(v, t);
    u.x += q.w * t.x; u.y += q.w * t.y; u.z += q.w * t.z;
    V3 c = v3cross(v, u);
    V3 r = {t.x + 2.f * c.x, t.y + 2.f * c.y, t.z + 2.f * c.z};
    return r;
}

__device__ __forceinline__ V3 quat_log(Q4 q) {
    float s = (q.w < 0.f) ? -1.f : 1.f;
    float x = q.x * s, y = q.y * s, z = q.z * s, w = q.w * s;
    float nv2 = x * x + y * y + z * z;
    float nv = sqrtf(fmaxf(nv2, 1e-14f));
    float angle = 2.f * atan2f(nv, w);
    float w_safe = (fabsf(w) > 1e-8f) ? w : 1.f;
    float scale = (nv < 1e-6f) ? (2.f / w_safe) : (angle / nv);
    V3 r = {x * scale, y * scale, z * scale};
    return r;
}

__device__ __forceinline__ void se3_log(V3 t, Q4 q, float* o6) {
    V3 phi = quat_log(q);
    float th2 = phi.x * phi.x + phi.y * phi.y + phi.z * phi.z;
    float th = sqrtf(fmaxf(th2, 1e-14f));
    bool small = th < 1e-4f;
    float ths = small ? 1.f : th;
    float sn = __sinf(ths), cs = __cosf(ths);
    float a_big = (1.f - ths * sn / (2.f * (1.f - cs))) / (ths * ths);
    float a = small ? (1.f / 12.f + th2 / 720.f) : a_big;
    V3 pt = v3cross(phi, t);
    V3 ppt = v3cross(phi, pt);
    o6[0] = t.x - 0.5f * pt.x + a * ppt.x;
    o6[1] = t.y - 0.5f * pt.y + a * ppt.y;
    o6[2] = t.z - 0.5f * pt.z + a * ppt.z;
    o6[3] = phi.x;
    o6[4] = phi.y;
    o6[5] = phi.z;
}

__global__ __launch_bounds__(BLK) void ik_kernel(
    const float* __restrict__ cfg,    // (B,32) f32
    const float* __restrict__ base,   // (B,7)  f32
    const float* __restrict__ tposes, // (4,7)
    const float* __restrict__ dbase,  // (7,)
    const float* __restrict__ restc,  // (32,)
    const float* __restrict__ joff,   // (32,7)
    const float* __restrict__ jaxes,  // (32,3)
    const float* __restrict__ jlo,    // (32,)
    const float* __restrict__ jup,    // (32,)
    float* __restrict__ out)          // (B,94) f32
{
    __shared__ float s_mt[NJ][3];     // per-joint local translation (= off_t)
    __shared__ float s_oq[NJ][4];     // offset quat
    __shared__ float s_ax[NJ][3];     // joint axis
    __shared__ float s_lo[NJ];
    __shared__ float s_up[NJ];
    __shared__ float s_rest[NJ];
    __shared__ float s_ti[4][7];      // inverse target poses
    __shared__ float s_dbi[7];        // inverse default base
    __shared__ __align__(8)  float s_base[ROWS_PER_BLK * 7];       // 1792 B
    __shared__ __align__(16) float s_out[ROWS_PER_BLK * 94];       // 24064 B

    const int tid = threadIdx.x;

    if (tid < NJ) {
        const int j = tid;
        s_mt[j][0] = joff[j * 7 + 0];
        s_mt[j][1] = joff[j * 7 + 1];
        s_mt[j][2] = joff[j * 7 + 2];
        s_oq[j][0] = joff[j * 7 + 3];
        s_oq[j][1] = joff[j * 7 + 4];
        s_oq[j][2] = joff[j * 7 + 5];
        s_oq[j][3] = joff[j * 7 + 6];
        s_ax[j][0] = jaxes[j * 3 + 0];
        s_ax[j][1] = jaxes[j * 3 + 1];
        s_ax[j][2] = jaxes[j * 3 + 2];
        s_lo[j] = jlo[j];
        s_up[j] = jup[j];
        s_rest[j] = restc[j];
    } else if (tid < 36) {
        const int i = tid - 32;
        V3 t = {tposes[i * 7 + 0], tposes[i * 7 + 1], tposes[i * 7 + 2]};
        Q4 q = {tposes[i * 7 + 3], tposes[i * 7 + 4], tposes[i * 7 + 5], tposes[i * 7 + 6]};
        Q4 qi = {-q.x, -q.y, -q.z, q.w};
        V3 rt = qrot(qi, t);
        s_ti[i][0] = -rt.x; s_ti[i][1] = -rt.y; s_ti[i][2] = -rt.z;
        s_ti[i][3] = qi.x;  s_ti[i][4] = qi.y;  s_ti[i][5] = qi.z;  s_ti[i][6] = qi.w;
    } else if (tid == 36) {
        V3 t = {dbase[0], dbase[1], dbase[2]};
        Q4 q = {dbase[3], dbase[4], dbase[5], dbase[6]};
        Q4 qi = {-q.x, -q.y, -q.z, q.w};
        V3 rt = qrot(qi, t);
        s_dbi[0] = -rt.x; s_dbi[1] = -rt.y; s_dbi[2] = -rt.z;
        s_dbi[3] = qi.x;  s_dbi[4] = qi.y;  s_dbi[5] = qi.z;  s_dbi[6] = qi.w;
    }
    // stage this block's 64 base poses (448 floats) coalesced
    if (tid < 224) {
        reinterpret_cast<float2*>(s_base)[tid] =
            reinterpret_cast<const float2*>(base + (size_t)blockIdx.x * ROWS_PER_BLK * 7)[tid];
    }
    __syncthreads();

    const int r   = tid >> 2;     // row within block
    const int sub = tid & 3;      // lane within row (= target index)
    const size_t b = (size_t)blockIdx.x * ROWS_PER_BLK + r;
    const int j0 = sub * 8;       // first joint of this lane's segment

    // ---- cfg segment: 8 f32, two coalesced float4 loads ----
    float cf[8];
    {
        const float4* cp = reinterpret_cast<const float4*>(cfg + b * NJ + j0);
        float4 c0 = cp[0], c1 = cp[1];
        cf[0] = c0.x; cf[1] = c0.y; cf[2] = c0.z; cf[3] = c0.w;
        cf[4] = c1.x; cf[5] = c1.y; cf[6] = c1.z; cf[7] = c1.w;
    }

    // ---- segment product S = M_{j0} ∘ ... ∘ M_{j0+7},  M_j = (off_t_j, off_q_j * jq_j) ----
    V3 St; Q4 Sq;
    {
        float half = 0.5f * cf[0];
        float sh = __sinf(half), ch = __cosf(half);
        Q4 jq = {s_ax[j0][0] * sh, s_ax[j0][1] * sh, s_ax[j0][2] * sh, ch};
        Q4 oq = {s_oq[j0][0], s_oq[j0][1], s_oq[j0][2], s_oq[j0][3]};
        Sq = qmul(oq, jq);
        St.x = s_mt[j0][0]; St.y = s_mt[j0][1]; St.z = s_mt[j0][2];
    }
    #pragma unroll
    for (int k = 1; k < 8; ++k) {
        const int j = j0 + k;
        float half = 0.5f * cf[k];
        float sh = __sinf(half), ch = __cosf(half);
        Q4 jq = {s_ax[j][0] * sh, s_ax[j][1] * sh, s_ax[j][2] * sh, ch};
        Q4 oq = {s_oq[j][0], s_oq[j][1], s_oq[j][2], s_oq[j][3]};
        Q4 mq = qmul(oq, jq);
        V3 mt = {s_mt[j][0], s_mt[j][1], s_mt[j][2]};
        V3 rt = qrot(Sq, mt);
        St.x += rt.x; St.y += rt.y; St.z += rt.z;
        Sq = qmul(Sq, mq);
    }

    // ---- inclusive prefix compose across the 4 lanes of this row ----
    #pragma unroll
    for (int d = 1; d <= 2; d <<= 1) {
        V3 Ut; Q4 Uq;
        Ut.x = __shfl_up(St.x, d, 4);
        Ut.y = __shfl_up(St.y, d, 4);
        Ut.z = __shfl_up(St.z, d, 4);
        Uq.x = __shfl_up(Sq.x, d, 4);
        Uq.y = __shfl_up(Sq.y, d, 4);
        Uq.z = __shfl_up(Sq.z, d, 4);
        Uq.w = __shfl_up(Sq.w, d, 4);
        V3 ct = qrot(Uq, St);
        ct.x += Ut.x; ct.y += Ut.y; ct.z += Ut.z;
        Q4 cq = qmul(Uq, Sq);
        bool take = (sub >= d);
        St.x = take ? ct.x : St.x; St.y = take ? ct.y : St.y; St.z = take ? ct.z : St.z;
        Sq.x = take ? cq.x : Sq.x; Sq.y = take ? cq.y : Sq.y;
        Sq.z = take ? cq.z : Sq.z; Sq.w = take ? cq.w : Sq.w;
    }

    // ---- pre-compose base: T = base ∘ P ----
    V3 b_t = {s_base[r * 7 + 0], s_base[r * 7 + 1], s_base[r * 7 + 2]};
    Q4 b_q = {s_base[r * 7 + 3], s_base[r * 7 + 4], s_base[r * 7 + 5], s_base[r * 7 + 6]};
    V3 Tt = qrot(b_q, St);
    Tt.x += b_t.x; Tt.y += b_t.y; Tt.z += b_t.z;
    Q4 Tq = qmul(b_q, Sq);

    float* o = s_out + r * 94;

    // ---- pose residual for this lane's target ----
    {
        V3 it = {s_ti[sub][0], s_ti[sub][1], s_ti[sub][2]};
        Q4 iq = {s_ti[sub][3], s_ti[sub][4], s_ti[sub][5], s_ti[sub][6]};
        V3 et = qrot(iq, Tt);
        et.x += it.x; et.y += it.y; et.z += it.z;
        Q4 eq = qmul(iq, Tq);
        float l6[6];
        se3_log(et, eq, l6);
        o[sub * 6 + 0] = l6[0];          // POS_W * POSE_W = 1.0
        o[sub * 6 + 1] = l6[1];
        o[sub * 6 + 2] = l6[2];
        o[sub * 6 + 3] = l6[3] * 0.5f;   // ORI_W * POSE_W = 0.5
        o[sub * 6 + 4] = l6[4] * 0.5f;
        o[sub * 6 + 5] = l6[5] * 0.5f;
    }

    // ---- limit + rest residuals for this lane's 8 joints ----
    #pragma unroll
    for (int k = 0; k < 8; ++k) {
        const int j = j0 + k;
        float c = cf[k];
        float lim = (fmaxf(c - s_up[j], 0.f) + fminf(c - s_lo[j], 0.f)) * 10.f;
        o[24 + j] = lim;
        o[56 + j] = (c - s_rest[j]) * 0.1f;
    }

    // ---- base residual (lane 0 only) ----
    if (sub == 0) {
        V3 it = {s_dbi[0], s_dbi[1], s_dbi[2]};
        Q4 iq = {s_dbi[3], s_dbi[4], s_dbi[5], s_dbi[6]};
        V3 et = qrot(iq, b_t);
        et.x += it.x; et.y += it.y; et.z += it.z;
        Q4 eq = qmul(iq, b_q);
        float l6[6];
        se3_log(et, eq, l6);
        o[88] = l6[0] * 5.f;
        o[89] = l6[1] * 5.f;
        o[90] = l6[2] * 5.f;
        o[91] = l6[3] * 5.f;
        o[92] = l6[4] * 5.f;
        o[93] = l6[5] * 5.f;
    }

    __syncthreads();

    // ---- coalesced flush: 64 rows * 94 f32 = 24064 B = 1504 uint4 ----
    {
        const uint4* src = reinterpret_cast<const uint4*>(s_out);
        uint4* dst = reinterpret_cast<uint4*>(out + (size_t)blockIdx.x * ROWS_PER_BLK * 94);
        #pragma unroll
        for (int i = 0; i < 6; ++i) {
            int idx = i * BLK + tid;
            if (idx < 1504) dst[idx] = src[idx];
        }
    }
}

extern "C" void kernel_launch(void* const* d_in, const int* in_sizes, int n_in,
                              void* d_out, int out_size, void* d_ws, size_t ws_size,
                              hipStream_t stream) {
    const float* cfg   = (const float*)d_in[0];
    const float* base  = (const float*)d_in[1];
    const float* tp    = (const float*)d_in[2];
    const float* db    = (const float*)d_in[3];
    const float* rest  = (const float*)d_in[4];
    const float* joff  = (const float*)d_in[5];
    const float* jax   = (const float*)d_in[6];
    const float* jlo   = (const float*)d_in[7];
    const float* jup   = (const float*)d_in[8];
    float* out = (float*)d_out;

    ik_kernel<<<NB / ROWS_PER_BLK, BLK, 0, stream>>>(cfg, base, tp, db, rest, joff, jax, jlo, jup, out);
}